// Round 4
// baseline (717.387 us; speedup 1.0000x reference)
//
#include <hip/hip_runtime.h>
#include <stdint.h>

#define TOKENS 65536
#define KDIM 1024
#define NDIM 1024
#define MROWS 65792            // TOKENS + 256, multiple of 256 (gap=256 -> no straddle at BM=256)
#define ROWTILES 257           // MROWS / 256
#define NTILES 4               // NDIM / 256
#define NWG (ROWTILES * NTILES)
#define BK 64

using short8 = __attribute__((ext_vector_type(8))) short;
using f32x4  = __attribute__((ext_vector_type(4))) float;

// async global->LDS, 16B per lane; LDS dest must be wave-uniform base (+lane*16 in HW)
#define ASYNC_COPY16(g, l) __builtin_amdgcn_global_load_lds( \
    (const __attribute__((address_space(1))) void*)(g),      \
    (__attribute__((address_space(3))) void*)(l), 16, 0, 0)

__device__ __forceinline__ short f2bf(float f) {
    union { float f; unsigned u; } c; c.f = f;
    unsigned r = c.u + 0x7FFFu + ((c.u >> 16) & 1u);   // round-to-nearest-even
    return (short)(r >> 16);
}

// ---------- mask format detection (runtime, value-based — verified) ----------
__global__ __launch_bounds__(256) void detect_mask_fmt(const unsigned* __restrict__ mask,
                                                       int* __restrict__ hdr) {
    int i = blockIdx.x * 256 + threadIdx.x;
    unsigned w = mask[i];
    int mode = 0;
    if (w == 0x3F800000u)      mode = 2;              // float 1.0
    else if (w > 1u)           mode = 1;              // packed bool bytes
    if (mode) atomicMax(&hdr[2], mode);
}

__device__ __forceinline__ bool read_mask(const void* mask, int fmt, int t) {
    if (fmt == 2) return ((const float*)mask)[t] != 0.0f;
    if (fmt == 1) return ((const unsigned char*)mask)[t] != 0;
    return ((const int*)mask)[t] != 0;
}

// ---------- slot assignment: visual ascending from 0, text descending from MROWS-1 ----------
__global__ __launch_bounds__(256) void route_assign(const void* __restrict__ mask,
                                                    int* __restrict__ rowmap,
                                                    int* __restrict__ hdr) {
    const int tid  = threadIdx.x;
    const int lane = tid & 63;
    const int wid  = tid >> 6;
    const int t    = blockIdx.x * 256 + tid;
    const int fmt  = hdr[2];
    const bool m   = read_mask(mask, fmt, t);

    unsigned long long bal = __ballot(m);
    int vpre = __popcll(bal & ((1ull << lane) - 1ull));
    int vcnt = __popcll(bal);
    int tpre = lane - vpre;
    int tcnt = 64 - vcnt;

    __shared__ int cv[4], ct[4], ov[4], ot[4];
    __shared__ int bv, bt;
    if (lane == 0) { cv[wid] = vcnt; ct[wid] = tcnt; }
    __syncthreads();
    if (tid == 0) {
        int sv = 0, st = 0;
        for (int w = 0; w < 4; ++w) { ov[w] = sv; sv += cv[w]; ot[w] = st; st += ct[w]; }
        bv = atomicAdd(&hdr[0], sv);   // hdr[0] ends as Mv
        bt = atomicAdd(&hdr[1], st);
    }
    __syncthreads();
    int slot = m ? (bv + ov[wid] + vpre)
                 : (MROWS - 1 - (bt + ot[wid] + tpre));
    rowmap[slot] = t;
}

// ---------- weights fp32 -> bf16 ----------
__global__ __launch_bounds__(256) void convert_weights(const float* __restrict__ wv,
                                                       const float* __restrict__ wt,
                                                       short* __restrict__ ovp,
                                                       short* __restrict__ otp) {
    int i = (blockIdx.x * 256 + threadIdx.x) * 4;
    const float* src; short* dst; int off;
    if (i < NDIM * KDIM) { src = wv; dst = ovp; off = i; }
    else                 { src = wt; dst = otp; off = i - NDIM * KDIM; }
    float4 v = *(const float4*)(src + off);
    short4 o;
    o.x = f2bf(v.x); o.y = f2bf(v.y); o.z = f2bf(v.z); o.w = f2bf(v.w);
    *(short4*)(dst + off) = o;
}

// ============ fused routed GEMM: A gathered from x (fp32) + converted in-kernel ============
// 256x256 tile, 8 waves (2Mx4N), per-wave 128x64, BK=64, dbuf LDS.
// A LDS layout: fragment-native [frag=(m_global*2+ks)][lane][16B] -> lane-linear ds_read, 0 conflicts.
// A staged via registers: 8x float4 loads of x[rowmap[row]] issued at ph1 (tile j+2), converted +
// ds_written at the j boundary (A-region of target buf read-free after ph3; barrier-separated).
// B: gload_lds with pre-swizzled source + XOR read (verified: conflicts=0).
// vmcnt: per-ktile issue order [A8(j+2)@ph1, B2@ph2, B2@ph3]; boundary vmcnt(4) retires A8(j+2)
// and everything older (incl. B(j+1)); reg-load deps additionally compiler-guarded.

#define QUAD(MB, NB)                                                              \
    do {                                                                          \
        _Pragma("unroll") for (int m_ = 0; m_ < 4; ++m_)                          \
        _Pragma("unroll") for (int n_ = 0; n_ < 2; ++n_)                          \
        _Pragma("unroll") for (int ks_ = 0; ks_ < 2; ++ks_)                       \
            acc[(MB) + m_][(NB) + n_] = __builtin_amdgcn_mfma_f32_16x16x32_bf16(  \
                a[2 * m_ + ks_], b[2 * ((NB) + n_) + ks_],                        \
                acc[(MB) + m_][(NB) + n_], 0, 0, 0);                              \
    } while (0)

__device__ __forceinline__ void wbA(char* dst, const float4 (&ast)[8]) {
#pragma unroll
    for (int q = 0; q < 4; ++q) {
        short8 o;
        o[0] = f2bf(ast[2*q].x);   o[1] = f2bf(ast[2*q].y);
        o[2] = f2bf(ast[2*q].z);   o[3] = f2bf(ast[2*q].w);
        o[4] = f2bf(ast[2*q+1].x); o[5] = f2bf(ast[2*q+1].y);
        o[6] = f2bf(ast[2*q+1].z); o[7] = f2bf(ast[2*q+1].w);
        *(short8*)(dst + q * 256) = o;
    }
}

template<bool ISSUE, int ENDM>  // ENDM 0: vmcnt(4)+WB+bar; 1: vmcnt(0)+bar (no WB); 2: none
__device__ __forceinline__ void kstep(const char* pA, const char* pB, char* lB, char* aWB,
                                      const float* xrow, int kf2, const short* bS2,
                                      f32x4 (&acc)[8][4], int xorhi) {
    short8 a[8], b[8];
    float4 ast[8];
    // ---- ph1: issue A(j+2) reg loads; ds_read A-frags m0..3 + all B-frags
    if (ISSUE) {
#pragma unroll
        for (int i = 0; i < 8; ++i) ast[i] = *(const float4*)(xrow + kf2 + 4 * i);
    }
#pragma unroll
    for (int m = 0; m < 4; ++m) {
        a[2*m]   = *(const short8*)(pA + (2*m)     * 1024);
        a[2*m+1] = *(const short8*)(pA + (2*m + 1) * 1024);
    }
#pragma unroll
    for (int n = 0; n < 4; ++n) {
        b[2*n]   = *(const short8*)(pB + n * 2048 + (0  ^ xorhi));
        b[2*n+1] = *(const short8*)(pB + n * 2048 + (64 ^ xorhi));
    }
    __builtin_amdgcn_s_barrier();
    asm volatile("s_waitcnt lgkmcnt(0)" ::: "memory");
    __builtin_amdgcn_sched_barrier(0);
    __builtin_amdgcn_s_setprio(1);  QUAD(0, 0);  __builtin_amdgcn_s_setprio(0);
    __builtin_amdgcn_s_barrier();
    // ---- ph2: stage B(j+2) half0 (B-region of this buf fully read in ph1)
    if (ISSUE) {
        ASYNC_COPY16(bS2,                     lB);
        ASYNC_COPY16(bS2 + (size_t)64 * KDIM, lB + 8192);
    }
    __builtin_amdgcn_s_setprio(1);  QUAD(0, 2);  __builtin_amdgcn_s_setprio(0);
    __builtin_amdgcn_s_barrier();
    // ---- ph3: ds_read A-frags m4..7; stage B(j+2) half1
#pragma unroll
    for (int m = 0; m < 4; ++m) {
        a[2*m]   = *(const short8*)(pA + (8 + 2*m) * 1024);
        a[2*m+1] = *(const short8*)(pA + (9 + 2*m) * 1024);
    }
    if (ISSUE) {
        ASYNC_COPY16(bS2 + (size_t)128 * KDIM, lB + 16384);
        ASYNC_COPY16(bS2 + (size_t)192 * KDIM, lB + 16384 + 8192);
    }
    __builtin_amdgcn_s_barrier();
    asm volatile("s_waitcnt lgkmcnt(0)" ::: "memory");
    __builtin_amdgcn_sched_barrier(0);
    __builtin_amdgcn_s_setprio(1);  QUAD(4, 0);  __builtin_amdgcn_s_setprio(0);
    __builtin_amdgcn_s_barrier();
    // ---- ph4 + boundary
    __builtin_amdgcn_s_setprio(1);  QUAD(4, 2);  __builtin_amdgcn_s_setprio(0);
    if (ENDM == 0) {
        asm volatile("s_waitcnt vmcnt(4)" ::: "memory");   // A8(j+2) + B(j+1) retired; B4(j+2) may fly
        wbA(aWB, ast);                                      // convert + ds_write A(j+2) (read-free region)
        asm volatile("s_waitcnt lgkmcnt(0)" ::: "memory");
        __builtin_amdgcn_s_barrier();
    } else if (ENDM == 1) {
        asm volatile("s_waitcnt vmcnt(0)" ::: "memory");
        __builtin_amdgcn_s_barrier();
    }
}

__global__ __launch_bounds__(512, 2) void gemm_routed(const float* __restrict__ x,
                                                      const short* __restrict__ Wv,
                                                      const short* __restrict__ Wt,
                                                      const int* __restrict__ rowmap,
                                                      const int* __restrict__ hdr,
                                                      float* __restrict__ out) {
    __shared__ __align__(16) short As[2 * 256 * 64];   // 64 KB, frag-native layout per buf
    __shared__ __align__(16) short Bs[2 * 256 * 64];   // 64 KB, row-major + XOR swizzle
    __shared__ int rmap_s[256];

    // bijective XCD swizzle (NWG=1028: q=128, r=4)
    const int q = NWG / 8, r = NWG % 8;
    const int xcd = blockIdx.x & 7, ii = blockIdx.x >> 3;
    const int wgid = (xcd < r ? xcd * (q + 1) : r * (q + 1) + (xcd - r) * q) + ii;
    const int r0 = (wgid >> 2) * 256;
    const int n0 = (wgid & 3) * 256;

    const int Mv = hdr[0];
    if (r0 == Mv) return;                          // gap-only tile (uniform exit, before any barrier)
    const short* Wsel = (r0 < Mv) ? Wv : Wt;       // straddle tiles: real rows one-sided, pads skipped

    const int tid  = threadIdx.x;
    const int lane = tid & 63;
    const int wvid = tid >> 6;
    const int wr   = wvid >> 2;                    // 0..1: 128-row half
    const int wc   = wvid & 3;                     // 0..3: 64-col quarter

    if (tid < 256) rmap_s[tid] = rowmap[r0 + tid];
    __syncthreads();

    // ---- A staging (reg path): thread covers row=tid>>1 (0..255), half=tid&1 (32 k-floats)
    const int arow = tid >> 1, ahalf = tid & 1;
    int tok = rmap_s[arow]; if (tok < 0) tok = 0;  // pad rows: load valid garbage, discarded at scatter
    const float* xrow = x + (size_t)tok * KDIM + ahalf * 32;
    // frag-native LDS dest: frag=(arow>>4)*2+ahalf, lane slot=(arow&15)+16q
    char* aWB0 = (char*)As + ((arow >> 4) * 2 + ahalf) * 1024 + (arow & 15) * 16;
    char* aWB1 = aWB0 + 32768;

    // ---- B staging (gload_lds): thread covers row=tid>>3, pre-swizzled chunk
    const int brow = tid >> 3;
    const int bchk = (tid & 7) ^ (brow & 7);       // inverse of read-side XOR
    const short* bSrc = Wsel + (size_t)(n0 + brow) * KDIM + bchk * 8;
    char* lB0 = (char*)Bs + wvid * 1024;           // wave-uniform dest (lane*16 by HW)
    char* lB1 = lB0 + 32768;

    // ---- fragment read bases
    const int xorhi = (lane & 4) << 4;
    const char* pA0 = (const char*)As + wr * 16384 + lane * 16;   // frag-major, lane-linear
    const char* pA1 = pA0 + 32768;
    const char* bRd = (const char*)Bs + (wc >> 1) * 16384
                      + (((wc & 1) * 64 + (lane & 15)) * 128)
                      + (((lane >> 4) * 16) ^ ((lane & 3) << 4));
    const char* pB0 = bRd;
    const char* pB1 = bRd + 32768;

    f32x4 acc[8][4];
#pragma unroll
    for (int m = 0; m < 8; ++m)
#pragma unroll
        for (int n = 0; n < 4; ++n) acc[m][n] = f32x4{0.f, 0.f, 0.f, 0.f};

    // ---- prologue: A(0),A(1) via regs; B(0),B(1) via gload_lds; full drain once
    {
        float4 ast[8];
#pragma unroll
        for (int i = 0; i < 8; ++i) ast[i] = *(const float4*)(xrow + 0 * BK + 4 * i);
        ASYNC_COPY16(bSrc + 0 * BK,                     lB0);
        ASYNC_COPY16(bSrc + 0 * BK + (size_t)64 * KDIM, lB0 + 8192);
        ASYNC_COPY16(bSrc + 0 * BK + (size_t)128 * KDIM, lB0 + 16384);
        ASYNC_COPY16(bSrc + 0 * BK + (size_t)192 * KDIM, lB0 + 16384 + 8192);
        ASYNC_COPY16(bSrc + 1 * BK,                     lB1);
        ASYNC_COPY16(bSrc + 1 * BK + (size_t)64 * KDIM, lB1 + 8192);
        ASYNC_COPY16(bSrc + 1 * BK + (size_t)128 * KDIM, lB1 + 16384);
        ASYNC_COPY16(bSrc + 1 * BK + (size_t)192 * KDIM, lB1 + 16384 + 8192);
        wbA(aWB0, ast);                            // compiler waits the reg loads
#pragma unroll
        for (int i = 0; i < 8; ++i) ast[i] = *(const float4*)(xrow + 1 * BK + 4 * i);
        wbA(aWB1, ast);
        asm volatile("s_waitcnt vmcnt(0) lgkmcnt(0)" ::: "memory");
        __builtin_amdgcn_s_barrier();
    }

    // ---- main loop: j0; pairs j1..j12; j13; j14; j15
    kstep<true, 0>(pA0, pB0, lB0, aWB0, xrow,  2 * BK, bSrc + (size_t)2 * BK, acc, xorhi);   // j0
    for (int it = 0; it < 6; ++it) {
        kstep<true, 0>(pA1, pB1, lB1, aWB1, xrow, (2*it+3) * BK, bSrc + (size_t)(2*it+3) * BK, acc, xorhi);
        kstep<true, 0>(pA0, pB0, lB0, aWB0, xrow, (2*it+4) * BK, bSrc + (size_t)(2*it+4) * BK, acc, xorhi);
    }
    kstep<true, 0>(pA1, pB1, lB1, aWB1, xrow, 15 * BK, bSrc + (size_t)15 * BK, acc, xorhi);  // j13
    kstep<false, 1>(pA0, pB0, lB0, aWB0, xrow, 0, bSrc, acc, xorhi);                         // j14
    kstep<false, 2>(pA1, pB1, lB1, aWB1, xrow, 0, bSrc, acc, xorhi);                         // j15

    // ---- epilogue: C/D layout col=lane&15, row=(lane>>4)*4+reg; scatter by rowmap
    const int colbase = n0 + wc * 64 + (lane & 15);
#pragma unroll
    for (int m = 0; m < 8; ++m) {
        const int rb = wr * 128 + m * 16 + ((lane >> 4) << 2);
#pragma unroll
        for (int i2 = 0; i2 < 4; ++i2) {
            int token = rmap_s[rb + i2];
            if (token < 0) continue;               // padding row
            float* orow = out + (size_t)token * NDIM + colbase;
            orow[0]  = acc[m][0][i2];
            orow[16] = acc[m][1][i2];
            orow[32] = acc[m][2][i2];
            orow[48] = acc[m][3][i2];
        }
    }
}

// ---------- fp32 fallback (only if workspace too small) ----------
__global__ __launch_bounds__(256) void fallback_matvec(const float* __restrict__ x,
                                                       const void* __restrict__ mask,
                                                       const float* __restrict__ wv,
                                                       const float* __restrict__ wt,
                                                       const int* __restrict__ hdr,
                                                       float* __restrict__ out) {
    __shared__ float xs[KDIM];
    const int t = blockIdx.x;
    const int fmt = hdr[2];
    const bool m = read_mask(mask, fmt, t);
    const float* w = m ? wv : wt;
    const float* src = x + (size_t)t * KDIM;
    for (int k = threadIdx.x; k < KDIM; k += 256) xs[k] = src[k];
    __syncthreads();
    for (int n = threadIdx.x; n < NDIM; n += 256) {
        const float* wr = w + (size_t)n * KDIM;
        float s = 0.f;
        for (int k = 0; k < KDIM; ++k) s += xs[k] * wr[k];
        out[(size_t)t * NDIM + n] = s;
    }
}

extern "C" void kernel_launch(void* const* d_in, const int* in_sizes, int n_in,
                              void* d_out, int out_size, void* d_ws, size_t ws_size,
                              hipStream_t stream) {
    const float* x    = (const float*)d_in[0];
    const void*  mask = d_in[1];
    const float* w_v  = (const float*)d_in[2];
    const float* w_t  = (const float*)d_in[3];
    float* out = (float*)d_out;

    char* ws = (char*)d_ws;
    // workspace layout (all 16B-aligned offsets)
    int*   hdr     = (int*)ws;                      // [0]=cnt_v [1]=cnt_t [2]=mask fmt
    int*   rowmap  = (int*)(ws + 4096);             // MROWS ints
    short* wvb     = (short*)(ws + 532480);         // 2 MB
    short* wtb     = (short*)(ws + 2629632);        // 2 MB
    const size_t need = 4726784ull;                 // no Abuf/slotmap needed anymore

    if (ws_size >= need) {
        hipMemsetAsync(hdr, 0, 16, stream);
        hipMemsetAsync(rowmap, 0xFF, MROWS * sizeof(int), stream);   // -1 sentinels
        detect_mask_fmt<<<64, 256, 0, stream>>>((const unsigned*)mask, hdr);
        route_assign<<<TOKENS / 256, 256, 0, stream>>>(mask, rowmap, hdr);
        convert_weights<<<(2 * NDIM * KDIM) / (256 * 4), 256, 0, stream>>>(w_v, w_t, wvb, wtb);
        gemm_routed<<<NWG, 512, 0, stream>>>(x, wvb, wtb, rowmap, hdr, out);
    } else {
        hipMemsetAsync(hdr, 0, 16, stream);
        detect_mask_fmt<<<64, 256, 0, stream>>>((const unsigned*)mask, hdr);
        fallback_matvec<<<TOKENS, 256, 0, stream>>>(x, mask, w_v, w_t, hdr, out);
    }
}